// Round 12
// baseline (364.777 us; speedup 1.0000x reference)
//
#include <hip/hip_runtime.h>
#include <hip/hip_fp16.h>

#define NFEAT 128
#define BSH 9          // bucket shift: 512 nodes per bucket
#define BSZ 512
#define EPB 2048       // edges per block in bucket passes

typedef _Float16 v8hf __attribute__((ext_vector_type(8)));
typedef _Float16 v4hf __attribute__((ext_vector_type(4)));
typedef float v4f __attribute__((ext_vector_type(4)));

// ---------------- wave-level inclusive scan (shuffle ladder) -----------------
__device__ __forceinline__ int wave_incl_scan(int v, int lane) {
  #pragma unroll
  for (int off = 1; off < 64; off <<= 1) {
    int t = __shfl_up(v, off, 64);
    if (lane >= off) v += t;
  }
  return v;
}

// ---- W transpose to fp16 + zero the bucket histogram ------------------------
__global__ __launch_bounds__(256) void k_wt(
    const float* __restrict__ W1, const float* __restrict__ W2,
    _Float16* __restrict__ Wt1, _Float16* __restrict__ Wt2,
    int* __restrict__ ghist) {
  int idx = blockIdx.x * 256 + threadIdx.x;
  if (idx < 32768) {
    const float* W = (idx < 16384) ? W1 : W2;
    _Float16* Wt = (idx < 16384) ? Wt1 : Wt2;
    int i = idx & 16383;
    int k = i >> 7, n = i & 127;
    Wt[n * 128 + k] = (_Float16)W[k * 128 + n];
  } else if (idx < 32768 + 256) {
    ghist[idx - 32768] = 0;
  }
}

// ---- coarse bucket histogram: LDS atomics + 1 global atomic per (blk,bucket)
__global__ __launch_bounds__(256) void k_bhist(const int* __restrict__ dst,
                                               int* __restrict__ ghist, int E) {
  __shared__ int h[256];
  const int tid = threadIdx.x;
  h[tid] = 0;
  __syncthreads();
  int e0 = blockIdx.x * EPB;
  #pragma unroll
  for (int i = 0; i < EPB / 256; i++) {
    int e = e0 + tid + i * 256;
    if (e < E) atomicAdd(&h[dst[e] >> BSH], 1);
  }
  __syncthreads();
  int c = h[tid];
  if (c) atomicAdd(&ghist[tid], c);
}

// ---- scan bucket totals: ebase (real edges), sbase (edges+selfs), cursor ----
__global__ __launch_bounds__(256) void k_bscan(
    const int* __restrict__ ghist, int* __restrict__ ebase,
    int* __restrict__ sbase, int* __restrict__ cursor,
    int* __restrict__ base, int nb, int N) {
  __shared__ int l1[4], l2[4];
  const int tid = threadIdx.x;
  const int lane = tid & 63;
  const int wv = tid >> 6;
  int ve = (tid < nb) ? ghist[tid] : 0;
  int selfc = 0;
  if (tid < nb) {
    int rem = N - (tid << BSH);
    selfc = (rem < BSZ) ? rem : BSZ;
  }
  int vs = ve + selfc;
  int ie = wave_incl_scan(ve, lane);
  int is = wave_incl_scan(vs, lane);
  if (lane == 63) { l1[wv] = ie; l2[wv] = is; }
  __syncthreads();
  int we = 0, ws = 0;
  #pragma unroll
  for (int w = 0; w < 4; w++) if (w < wv) { we += l1[w]; ws += l2[w]; }
  if (tid <= nb) {
    int eb = we + ie - ve;
    ebase[tid] = eb;
    cursor[tid] = eb;
    sbase[tid] = ws + is - vs;
    if (tid == nb) base[N] = ws + is - vs;   // also covers N % BSZ == 0
  }
}

// ---- partition edges into bucket order (packed (dst,src) 8-B records) -------
__global__ __launch_bounds__(256) void k_bscatter(
    const int* __restrict__ src, const int* __restrict__ dst,
    int* __restrict__ cursor, unsigned long long* __restrict__ epk, int E) {
  __shared__ int h[256];
  __shared__ int res[256];
  const int tid = threadIdx.x;
  h[tid] = 0;
  __syncthreads();
  int e0 = blockIdx.x * EPB;
  #pragma unroll
  for (int i = 0; i < EPB / 256; i++) {
    int e = e0 + tid + i * 256;
    if (e < E) atomicAdd(&h[dst[e] >> BSH], 1);
  }
  __syncthreads();
  int c = h[tid];
  if (c) res[tid] = atomicAdd(&cursor[tid], c);
  __syncthreads();
  h[tid] = 0;
  __syncthreads();
  #pragma unroll
  for (int i = 0; i < EPB / 256; i++) {
    int e = e0 + tid + i * 256;
    if (e < E) {
      int d = dst[e];
      int b = d >> BSH;
      int off = atomicAdd(&h[b], 1);
      epk[res[b] + off] =
          ((unsigned long long)(unsigned)d << 32) | (unsigned)src[e];
    }
  }
}

// ---- per-bucket: node histogram (LDS) -> deg/dinv/base + self + ssrc --------
__global__ __launch_bounds__(256) void k_bfinal(
    const unsigned long long* __restrict__ epk, const int* __restrict__ ebase,
    const int* __restrict__ sbase, int* __restrict__ base,
    float* __restrict__ dinv, int* __restrict__ ssrc, int N) {
  __shared__ int cnt[BSZ];
  __shared__ int ex[BSZ];
  __shared__ int lds[4];
  const int k = blockIdx.x;
  const int tid = threadIdx.x;
  const int lane = tid & 63;
  const int wv = tid >> 6;
  const int n0 = k << BSH;

  #pragma unroll
  for (int i = tid; i < BSZ; i += 256) cnt[i] = (n0 + i < N) ? 1 : 0;  // self
  __syncthreads();
  const int eb = ebase[k], ee = ebase[k + 1];
  for (int e = eb + tid; e < ee; e += 256) {
    int d = (int)(epk[e] >> 32);
    atomicAdd(&cnt[d - n0], 1);
  }
  __syncthreads();
  // exclusive scan of cnt[0..511] (2 elems/thread)
  int a = cnt[2 * tid], b = cnt[2 * tid + 1];
  int inc = wave_incl_scan(a + b, lane);
  if (lane == 63) lds[wv] = inc;
  __syncthreads();
  int woff = 0;
  #pragma unroll
  for (int w = 0; w < 4; w++) if (w < wv) woff += lds[w];
  int e0x = woff + inc - (a + b);
  ex[2 * tid] = e0x;
  ex[2 * tid + 1] = e0x + a;
  __syncthreads();

  const int sb = sbase[k];
  #pragma unroll
  for (int i = tid; i < BSZ; i += 256) {
    int n = n0 + i;
    if (n <= N) base[n] = sb + ex[i];
    if (n < N) {
      dinv[n] = rsqrtf((float)cnt[i]);   // cnt = degree incl self-loop
      ssrc[sb + ex[i]] = n;              // self edge in slot 0
      ex[i] = ex[i] + 1;                 // cursor past self (same-thread, safe)
    }
  }
  __syncthreads();
  for (int e = eb + tid; e < ee; e += 256) {
    unsigned long long p = epk[e];
    int d = (int)(p >> 32);
    int s = (int)(p & 0xffffffffu);
    int off = atomicAdd(&ex[d - n0], 1);
    ssrc[sb + off] = s;
  }
}

// ---------------- MFMA fp16 GEMM: g16[r][:] = half((A[r][:] @ W) * dinv[r]) --
template <typename AT>
__global__ __launch_bounds__(256) void k_gemm_mfma(
    const AT* __restrict__ A, const _Float16* __restrict__ Wt,
    const float* __restrict__ dinv, _Float16* __restrict__ g16, int N) {
  __shared__ _Float16 As[64][136];
  __shared__ _Float16 Ws[128][136];
  const int tid = threadIdx.x;
  const int row0 = blockIdx.x * 64;

  if (blockIdx.x == 0 && tid < 16) {   // zero sentinel row N
    v8hf z;
    #pragma unroll
    for (int j = 0; j < 8; j++) z[j] = (_Float16)0.f;
    *(v8hf*)(g16 + (size_t)N * NFEAT + tid * 8) = z;
  }

  if constexpr (sizeof(AT) == 4) {   // fp32 input: load + cast + packed 8B write
    #pragma unroll
    for (int i = 0; i < 8; i++) {
      int idx = tid + i * 256;       // 0..2047
      int row = idx >> 5;
      int c4 = idx & 31;
      int gr = row0 + row; gr = (gr < N) ? gr : (N - 1);
      float4 v = *(const float4*)((const float*)A + (size_t)gr * NFEAT + c4 * 4);
      v4hf h;
      h[0] = (_Float16)v.x; h[1] = (_Float16)v.y;
      h[2] = (_Float16)v.z; h[3] = (_Float16)v.w;
      *(v4hf*)&As[row][c4 * 4] = h;
    }
  } else {                           // fp16 input: straight 16B copies
    #pragma unroll
    for (int i = 0; i < 4; i++) {
      int idx = tid + i * 256;
      int row = idx >> 4;
      int c8 = idx & 15;
      int gr = row0 + row; gr = (gr < N) ? gr : (N - 1);
      *(uint4*)&As[row][c8 * 8] =
          *(const uint4*)((const _Float16*)A + (size_t)gr * NFEAT + c8 * 8);
    }
  }
  #pragma unroll
  for (int i = 0; i < 8; i++) {
    int idx = tid + i * 256;
    int row = idx >> 4;
    int c8 = idx & 15;
    *(uint4*)&Ws[row][c8 * 8] = *(const uint4*)(Wt + (size_t)row * 128 + c8 * 8);
  }
  __syncthreads();

  const int wv = tid >> 6;
  const int lane = tid & 63;
  const int m = lane & 15;
  const int q = lane >> 4;

  v4f acc[8] = {};
  const _Float16* arow = &As[wv * 16 + m][0];
  #pragma unroll
  for (int kt = 0; kt < 4; kt++) {
    v8hf af = *(const v8hf*)(arow + kt * 32 + q * 8);
    #pragma unroll
    for (int ct = 0; ct < 8; ct++) {
      v8hf bf = *(const v8hf*)(&Ws[ct * 16 + m][kt * 32 + q * 8]);
      acc[ct] = __builtin_amdgcn_mfma_f32_16x16x32_f16(af, bf, acc[ct], 0, 0, 0);
    }
  }

  float dv[4];
  #pragma unroll
  for (int r = 0; r < 4; r++) {
    int nd = row0 + wv * 16 + q * 4 + r;
    int c = (nd < N) ? nd : (N - 1);
    dv[r] = dinv[c];
  }

  __syncthreads();                   // all As reads complete -> reuse as C tile
  #pragma unroll
  for (int ct = 0; ct < 8; ct++)
    #pragma unroll
    for (int r = 0; r < 4; r++)
      As[wv * 16 + q * 4 + r][ct * 16 + m] = (_Float16)(acc[ct][r] * dv[r]);
  __syncthreads();

  #pragma unroll
  for (int i = 0; i < 4; i++) {
    int idx = tid + i * 256;         // 0..1023
    int row = idx >> 4;
    int c8 = idx & 15;
    int gr = row0 + row;
    if (gr < N)
      *(v8hf*)(g16 + (size_t)gr * NFEAT + c8 * 8) = *(const v8hf*)&As[row][c8 * 8];
  }
}

// ---------------- agg: wave per node, depth-2 pipelined gathers --------------
// 512-thread blocks (8 waves) -> up to 32 waves/CU (was 24 at 256): more TLP
// to cover the serial base->ssrc->gather prologue chain. ssrc reads and hB
// writes are nontemporal so streaming traffic doesn't evict gather lines.
__global__ __launch_bounds__(512, 8) void k_agg(
    const _Float16* __restrict__ g, const float* __restrict__ dinv,
    const int* __restrict__ base, const int* __restrict__ ssrc,
    const float* __restrict__ bias, _Float16* __restrict__ hB, int N) {
  const int lane = threadIdx.x & 63;
  const int n = blockIdx.x * 8 + (threadIdx.x >> 6);
  if (n >= N) return;
  const int gq = lane >> 4;
  const int l = lane & 15;
  const int b0 = base[n], b1 = base[n + 1];

  int e = b0;
  int p0 = e + gq, p1 = e + 4 + gq;
  int i0 = __builtin_nontemporal_load(ssrc + p0);   // +16 slack makes loads safe
  int i1 = __builtin_nontemporal_load(ssrc + p1);
  i0 = (p0 < b1) ? i0 : N;
  i1 = (p1 < b1) ? i1 : N;
  v8hf r0 = *(const v8hf*)(g + (size_t)i0 * NFEAT + l * 8);
  v8hf r1 = *(const v8hf*)(g + (size_t)i1 * NFEAT + l * 8);
  int e2 = e + 8;
  int j0 = N, j1 = N;
  if (e2 < b1) {
    int q0 = e2 + gq, q1 = e2 + 4 + gq;
    j0 = __builtin_nontemporal_load(ssrc + q0);
    j1 = __builtin_nontemporal_load(ssrc + q1);
    j0 = (q0 < b1) ? j0 : N;
    j1 = (q1 < b1) ? j1 : N;
  }

  float acc[8] = {};
  while (true) {
    bool more = (e2 < b1);
    v8hf s0, s1;
    if (more) {                       // issue iter k+1 gathers before consuming k
      s0 = *(const v8hf*)(g + (size_t)j0 * NFEAT + l * 8);
      s1 = *(const v8hf*)(g + (size_t)j1 * NFEAT + l * 8);
    }
    int e3 = e2 + 8;
    int c0 = N, c1 = N;
    if (e3 < b1) {                    // iter k+2 indices
      int q0 = e3 + gq, q1 = e3 + 4 + gq;
      c0 = __builtin_nontemporal_load(ssrc + q0);
      c1 = __builtin_nontemporal_load(ssrc + q1);
      c0 = (q0 < b1) ? c0 : N;
      c1 = (q1 < b1) ? c1 : N;
    }
    #pragma unroll
    for (int j = 0; j < 8; j++) acc[j] += (float)r0[j] + (float)r1[j];
    if (!more) break;
    r0 = s0; r1 = s1;
    j0 = c0; j1 = c1;
    e2 = e3;
  }

  #pragma unroll
  for (int j = 0; j < 8; j++) {
    acc[j] += __shfl_xor(acc[j], 16, 64);
    acc[j] += __shfl_xor(acc[j], 32, 64);
  }
  if (gq == 0) {
    float dvn = dinv[n];
    const float* bp = bias + l * 8;
    float4 bb0 = *(const float4*)(bp);
    float4 bb1 = *(const float4*)(bp + 4);
    float bv[8] = {bb0.x, bb0.y, bb0.z, bb0.w, bb1.x, bb1.y, bb1.z, bb1.w};
    v8hf o;
    #pragma unroll
    for (int j = 0; j < 8; j++)
      o[j] = (_Float16)fmaxf(acc[j] * dvn + bv[j], 0.f);
    __builtin_nontemporal_store(o, (v8hf*)(hB + (size_t)n * NFEAT + l * 8));
  }
}

// ---------------- layer-2 agg fused with final linear (same pipeline) --------
__global__ __launch_bounds__(512, 8) void k_agg_final(
    const _Float16* __restrict__ g, const float* __restrict__ dinv,
    const int* __restrict__ base, const int* __restrict__ ssrc,
    const float* __restrict__ bias, const float* __restrict__ wlin,
    const float* __restrict__ blin, float* __restrict__ out, int N) {
  const int lane = threadIdx.x & 63;
  const int n = blockIdx.x * 8 + (threadIdx.x >> 6);
  if (n >= N) return;
  const int gq = lane >> 4;
  const int l = lane & 15;
  const int b0 = base[n], b1 = base[n + 1];

  int e = b0;
  int p0 = e + gq, p1 = e + 4 + gq;
  int i0 = __builtin_nontemporal_load(ssrc + p0);
  int i1 = __builtin_nontemporal_load(ssrc + p1);
  i0 = (p0 < b1) ? i0 : N;
  i1 = (p1 < b1) ? i1 : N;
  v8hf r0 = *(const v8hf*)(g + (size_t)i0 * NFEAT + l * 8);
  v8hf r1 = *(const v8hf*)(g + (size_t)i1 * NFEAT + l * 8);
  int e2 = e + 8;
  int j0 = N, j1 = N;
  if (e2 < b1) {
    int q0 = e2 + gq, q1 = e2 + 4 + gq;
    j0 = __builtin_nontemporal_load(ssrc + q0);
    j1 = __builtin_nontemporal_load(ssrc + q1);
    j0 = (q0 < b1) ? j0 : N;
    j1 = (q1 < b1) ? j1 : N;
  }

  float acc[8] = {};
  while (true) {
    bool more = (e2 < b1);
    v8hf s0, s1;
    if (more) {
      s0 = *(const v8hf*)(g + (size_t)j0 * NFEAT + l * 8);
      s1 = *(const v8hf*)(g + (size_t)j1 * NFEAT + l * 8);
    }
    int e3 = e2 + 8;
    int c0 = N, c1 = N;
    if (e3 < b1) {
      int q0 = e3 + gq, q1 = e3 + 4 + gq;
      c0 = __builtin_nontemporal_load(ssrc + q0);
      c1 = __builtin_nontemporal_load(ssrc + q1);
      c0 = (q0 < b1) ? c0 : N;
      c1 = (q1 < b1) ? c1 : N;
    }
    #pragma unroll
    for (int j = 0; j < 8; j++) acc[j] += (float)r0[j] + (float)r1[j];
    if (!more) break;
    r0 = s0; r1 = s1;
    j0 = c0; j1 = c1;
    e2 = e3;
  }

  #pragma unroll
  for (int j = 0; j < 8; j++) {
    acc[j] += __shfl_xor(acc[j], 16, 64);
    acc[j] += __shfl_xor(acc[j], 32, 64);
  }
  float dvn = dinv[n];
  const float* bp = bias + l * 8;
  const float* wp = wlin + l * 8;
  float4 bb0 = *(const float4*)(bp);
  float4 bb1 = *(const float4*)(bp + 4);
  float4 wl0 = *(const float4*)(wp);
  float4 wl1 = *(const float4*)(wp + 4);
  float bv[8] = {bb0.x, bb0.y, bb0.z, bb0.w, bb1.x, bb1.y, bb1.z, bb1.w};
  float wv[8] = {wl0.x, wl0.y, wl0.z, wl0.w, wl1.x, wl1.y, wl1.z, wl1.w};
  float pv = 0.f;
  #pragma unroll
  for (int j = 0; j < 8; j++)
    pv += fmaxf(acc[j] * dvn + bv[j], 0.f) * wv[j];
  pv += __shfl_xor(pv, 1, 64);
  pv += __shfl_xor(pv, 2, 64);
  pv += __shfl_xor(pv, 4, 64);
  pv += __shfl_xor(pv, 8, 64);
  if (lane == 0) out[n] = pv + blin[0];
}

extern "C" void kernel_launch(void* const* d_in, const int* in_sizes, int n_in,
                              void* d_out, int out_size, void* d_ws, size_t ws_size,
                              hipStream_t stream) {
  const float* x    = (const float*)d_in[0];
  const int*   ei   = (const int*)d_in[1];
  const float* W1   = (const float*)d_in[2];
  const float* b1   = (const float*)d_in[3];
  const float* W2   = (const float*)d_in[4];
  const float* b2   = (const float*)d_in[5];
  const float* Wlin = (const float*)d_in[6];
  const float* blin = (const float*)d_in[7];
  const int N = in_sizes[0] / NFEAT;
  const int E = in_sizes[1] / 2;
  const int* src = ei;
  const int* dst = ei + E;
  const int Etot = E + N;                  // real edges + self edges
  const int nb = (N + BSZ - 1) >> BSH;     // #buckets (<=256 for N<=131072)

  // workspace layout (4B units)
  int* ws_i = (int*)d_ws;
  size_t off = 0;
  int* base    = ws_i + off; off += (size_t)N + 1;
  int* ghist   = ws_i + off; off += 256;
  int* ebase   = ws_i + off; off += 257;
  int* sbase   = ws_i + off; off += 257;
  int* cursor  = ws_i + off; off += 257;
  int* ssrc    = ws_i + off; off += Etot + 16;   // +16 slack for tail loads
  float* dinv  = (float*)(ws_i + off); off += N;
  off = (off + 3) & ~(size_t)3;
  _Float16* Wt1 = (_Float16*)(ws_i + off); off += 8192;  // 16384 halves
  _Float16* Wt2 = (_Float16*)(ws_i + off); off += 8192;
  _Float16* g16 = (_Float16*)(ws_i + off); off += (size_t)(N + 1) * 64; // +sentinel
  off = (off + 1) & ~(size_t)1;                  // 8B align for epk alias
  _Float16* hB  = (_Float16*)(ws_i + off); off += (size_t)N * 64;
  // epk aliases hB: written by k_bscatter, read by k_bfinal, dead before k_agg
  // writes hB. Needs Etot*8B = 13.3MB <= hB's 25.6MB.
  unsigned long long* epk = (unsigned long long*)hB;

  // 1. W transpose + zero bucket histogram
  k_wt<<<129, 256, 0, stream>>>(W1, W2, Wt1, Wt2, ghist);
  // 2. coarse bucket histogram (LDS atomics, 1 global atomic/(blk,bucket))
  const int ebg = (E + EPB - 1) / EPB;
  k_bhist<<<ebg, 256, 0, stream>>>(dst, ghist, E);
  // 3. scan bucket totals
  k_bscan<<<1, 256, 0, stream>>>(ghist, ebase, sbase, cursor, base, nb, N);
  // 4. partition edges into bucket order (packed 8B records)
  k_bscatter<<<ebg, 256, 0, stream>>>(src, dst, cursor, epk, E);
  // 5. per-bucket node histogram -> base/dinv/self/ssrc (all LDS atomics)
  k_bfinal<<<nb, 256, 0, stream>>>(epk, ebase, sbase, base, dinv, ssrc, N);

  const int gg = (N + 63) / 64;
  const int ga = (N + 7) / 8;
  // layer 1
  k_gemm_mfma<float><<<gg, 256, 0, stream>>>(x, Wt1, dinv, g16, N);
  k_agg<<<ga, 512, 0, stream>>>(g16, dinv, base, ssrc, b1, hB, N);
  // layer 2 + fused final linear
  k_gemm_mfma<_Float16><<<gg, 256, 0, stream>>>(hB, Wt2, dinv, g16, N);
  k_agg_final<<<ga, 512, 0, stream>>>(g16, dinv, base, ssrc, b2,
                                      Wlin, blin, (float*)d_out, N);
}

// Round 13
// 358.837 us; speedup vs baseline: 1.0166x; 1.0166x over previous
//
#include <hip/hip_runtime.h>
#include <hip/hip_fp16.h>

#define NFEAT 128
#define BSH 9          // bucket shift: 512 nodes per bucket
#define BSZ 512
#define EPB 2048       // edges per block in bucket passes

typedef _Float16 v8hf __attribute__((ext_vector_type(8)));
typedef _Float16 v4hf __attribute__((ext_vector_type(4)));
typedef float v4f __attribute__((ext_vector_type(4)));

// ---------------- wave-level inclusive scan (shuffle ladder) -----------------
__device__ __forceinline__ int wave_incl_scan(int v, int lane) {
  #pragma unroll
  for (int off = 1; off < 64; off <<= 1) {
    int t = __shfl_up(v, off, 64);
    if (lane >= off) v += t;
  }
  return v;
}

// ---- W transpose to fp16 + zero the bucket histogram ------------------------
__global__ __launch_bounds__(256) void k_wt(
    const float* __restrict__ W1, const float* __restrict__ W2,
    _Float16* __restrict__ Wt1, _Float16* __restrict__ Wt2,
    int* __restrict__ ghist) {
  int idx = blockIdx.x * 256 + threadIdx.x;
  if (idx < 32768) {
    const float* W = (idx < 16384) ? W1 : W2;
    _Float16* Wt = (idx < 16384) ? Wt1 : Wt2;
    int i = idx & 16383;
    int k = i >> 7, n = i & 127;
    Wt[n * 128 + k] = (_Float16)W[k * 128 + n];
  } else if (idx < 32768 + 256) {
    ghist[idx - 32768] = 0;
  }
}

// ---- coarse bucket histogram: LDS atomics + 1 global atomic per (blk,bucket)
__global__ __launch_bounds__(256) void k_bhist(const int* __restrict__ dst,
                                               int* __restrict__ ghist, int E) {
  __shared__ int h[256];
  const int tid = threadIdx.x;
  h[tid] = 0;
  __syncthreads();
  int e0 = blockIdx.x * EPB;
  #pragma unroll
  for (int i = 0; i < EPB / 256; i++) {
    int e = e0 + tid + i * 256;
    if (e < E) atomicAdd(&h[dst[e] >> BSH], 1);
  }
  __syncthreads();
  int c = h[tid];
  if (c) atomicAdd(&ghist[tid], c);
}

// ---- scan bucket totals: ebase (real edges), sbase (edges+selfs), cursor ----
__global__ __launch_bounds__(256) void k_bscan(
    const int* __restrict__ ghist, int* __restrict__ ebase,
    int* __restrict__ sbase, int* __restrict__ cursor,
    int* __restrict__ base, int nb, int N) {
  __shared__ int l1[4], l2[4];
  const int tid = threadIdx.x;
  const int lane = tid & 63;
  const int wv = tid >> 6;
  int ve = (tid < nb) ? ghist[tid] : 0;
  int selfc = 0;
  if (tid < nb) {
    int rem = N - (tid << BSH);
    selfc = (rem < BSZ) ? rem : BSZ;
  }
  int vs = ve + selfc;
  int ie = wave_incl_scan(ve, lane);
  int is = wave_incl_scan(vs, lane);
  if (lane == 63) { l1[wv] = ie; l2[wv] = is; }
  __syncthreads();
  int we = 0, ws = 0;
  #pragma unroll
  for (int w = 0; w < 4; w++) if (w < wv) { we += l1[w]; ws += l2[w]; }
  if (tid <= nb) {
    int eb = we + ie - ve;
    ebase[tid] = eb;
    cursor[tid] = eb;
    sbase[tid] = ws + is - vs;
    if (tid == nb) base[N] = ws + is - vs;   // also covers N % BSZ == 0
  }
}

// ---- partition edges into bucket order (packed (dst,src) 8-B records) -------
__global__ __launch_bounds__(256) void k_bscatter(
    const int* __restrict__ src, const int* __restrict__ dst,
    int* __restrict__ cursor, unsigned long long* __restrict__ epk, int E) {
  __shared__ int h[256];
  __shared__ int res[256];
  const int tid = threadIdx.x;
  h[tid] = 0;
  __syncthreads();
  int e0 = blockIdx.x * EPB;
  #pragma unroll
  for (int i = 0; i < EPB / 256; i++) {
    int e = e0 + tid + i * 256;
    if (e < E) atomicAdd(&h[dst[e] >> BSH], 1);
  }
  __syncthreads();
  int c = h[tid];
  if (c) res[tid] = atomicAdd(&cursor[tid], c);
  __syncthreads();
  h[tid] = 0;
  __syncthreads();
  #pragma unroll
  for (int i = 0; i < EPB / 256; i++) {
    int e = e0 + tid + i * 256;
    if (e < E) {
      int d = dst[e];
      int b = d >> BSH;
      int off = atomicAdd(&h[b], 1);
      epk[res[b] + off] =
          ((unsigned long long)(unsigned)d << 32) | (unsigned)src[e];
    }
  }
}

// ---- per-bucket: node histogram (LDS) -> deg/dinv/base + self + ssrc --------
__global__ __launch_bounds__(256) void k_bfinal(
    const unsigned long long* __restrict__ epk, const int* __restrict__ ebase,
    const int* __restrict__ sbase, int* __restrict__ base,
    float* __restrict__ dinv, int* __restrict__ ssrc, int N) {
  __shared__ int cnt[BSZ];
  __shared__ int ex[BSZ];
  __shared__ int lds[4];
  const int k = blockIdx.x;
  const int tid = threadIdx.x;
  const int lane = tid & 63;
  const int wv = tid >> 6;
  const int n0 = k << BSH;

  #pragma unroll
  for (int i = tid; i < BSZ; i += 256) cnt[i] = (n0 + i < N) ? 1 : 0;  // self
  __syncthreads();
  const int eb = ebase[k], ee = ebase[k + 1];
  for (int e = eb + tid; e < ee; e += 256) {
    int d = (int)(epk[e] >> 32);
    atomicAdd(&cnt[d - n0], 1);
  }
  __syncthreads();
  // exclusive scan of cnt[0..511] (2 elems/thread)
  int a = cnt[2 * tid], b = cnt[2 * tid + 1];
  int inc = wave_incl_scan(a + b, lane);
  if (lane == 63) lds[wv] = inc;
  __syncthreads();
  int woff = 0;
  #pragma unroll
  for (int w = 0; w < 4; w++) if (w < wv) woff += lds[w];
  int e0x = woff + inc - (a + b);
  ex[2 * tid] = e0x;
  ex[2 * tid + 1] = e0x + a;
  __syncthreads();

  const int sb = sbase[k];
  #pragma unroll
  for (int i = tid; i < BSZ; i += 256) {
    int n = n0 + i;
    if (n <= N) base[n] = sb + ex[i];
    if (n < N) {
      dinv[n] = rsqrtf((float)cnt[i]);   // cnt = degree incl self-loop
      ssrc[sb + ex[i]] = n;              // self edge in slot 0
      ex[i] = ex[i] + 1;                 // cursor past self (same-thread, safe)
    }
  }
  __syncthreads();
  for (int e = eb + tid; e < ee; e += 256) {
    unsigned long long p = epk[e];
    int d = (int)(p >> 32);
    int s = (int)(p & 0xffffffffu);
    int off = atomicAdd(&ex[d - n0], 1);
    ssrc[sb + off] = s;
  }
}

// ---------------- MFMA fp16 GEMM: g16[r][:] = half((A[r][:] @ W) * dinv[r]) --
template <typename AT>
__global__ __launch_bounds__(256) void k_gemm_mfma(
    const AT* __restrict__ A, const _Float16* __restrict__ Wt,
    const float* __restrict__ dinv, _Float16* __restrict__ g16, int N) {
  __shared__ _Float16 As[64][136];
  __shared__ _Float16 Ws[128][136];
  const int tid = threadIdx.x;
  const int row0 = blockIdx.x * 64;

  if (blockIdx.x == 0 && tid < 16) {   // zero sentinel row N
    v8hf z;
    #pragma unroll
    for (int j = 0; j < 8; j++) z[j] = (_Float16)0.f;
    *(v8hf*)(g16 + (size_t)N * NFEAT + tid * 8) = z;
  }

  if constexpr (sizeof(AT) == 4) {   // fp32 input: load + cast + packed 8B write
    #pragma unroll
    for (int i = 0; i < 8; i++) {
      int idx = tid + i * 256;       // 0..2047
      int row = idx >> 5;
      int c4 = idx & 31;
      int gr = row0 + row; gr = (gr < N) ? gr : (N - 1);
      float4 v = *(const float4*)((const float*)A + (size_t)gr * NFEAT + c4 * 4);
      v4hf h;
      h[0] = (_Float16)v.x; h[1] = (_Float16)v.y;
      h[2] = (_Float16)v.z; h[3] = (_Float16)v.w;
      *(v4hf*)&As[row][c4 * 4] = h;
    }
  } else {                           // fp16 input: straight 16B copies
    #pragma unroll
    for (int i = 0; i < 4; i++) {
      int idx = tid + i * 256;
      int row = idx >> 4;
      int c8 = idx & 15;
      int gr = row0 + row; gr = (gr < N) ? gr : (N - 1);
      *(uint4*)&As[row][c8 * 8] =
          *(const uint4*)((const _Float16*)A + (size_t)gr * NFEAT + c8 * 8);
    }
  }
  #pragma unroll
  for (int i = 0; i < 8; i++) {
    int idx = tid + i * 256;
    int row = idx >> 4;
    int c8 = idx & 15;
    *(uint4*)&Ws[row][c8 * 8] = *(const uint4*)(Wt + (size_t)row * 128 + c8 * 8);
  }
  __syncthreads();

  const int wv = tid >> 6;
  const int lane = tid & 63;
  const int m = lane & 15;
  const int q = lane >> 4;

  v4f acc[8] = {};
  const _Float16* arow = &As[wv * 16 + m][0];
  #pragma unroll
  for (int kt = 0; kt < 4; kt++) {
    v8hf af = *(const v8hf*)(arow + kt * 32 + q * 8);
    #pragma unroll
    for (int ct = 0; ct < 8; ct++) {
      v8hf bf = *(const v8hf*)(&Ws[ct * 16 + m][kt * 32 + q * 8]);
      acc[ct] = __builtin_amdgcn_mfma_f32_16x16x32_f16(af, bf, acc[ct], 0, 0, 0);
    }
  }

  float dv[4];
  #pragma unroll
  for (int r = 0; r < 4; r++) {
    int nd = row0 + wv * 16 + q * 4 + r;
    int c = (nd < N) ? nd : (N - 1);
    dv[r] = dinv[c];
  }

  __syncthreads();                   // all As reads complete -> reuse as C tile
  #pragma unroll
  for (int ct = 0; ct < 8; ct++)
    #pragma unroll
    for (int r = 0; r < 4; r++)
      As[wv * 16 + q * 4 + r][ct * 16 + m] = (_Float16)(acc[ct][r] * dv[r]);
  __syncthreads();

  #pragma unroll
  for (int i = 0; i < 4; i++) {
    int idx = tid + i * 256;         // 0..1023
    int row = idx >> 4;
    int c8 = idx & 15;
    int gr = row0 + row;
    if (gr < N)
      *(v8hf*)(g16 + (size_t)gr * NFEAT + c8 * 8) = *(const v8hf*)&As[row][c8 * 8];
  }
}

// ---------------- agg: wave per node, depth-2 pipelined gathers --------------
__global__ __launch_bounds__(256) void k_agg(
    const _Float16* __restrict__ g, const float* __restrict__ dinv,
    const int* __restrict__ base, const int* __restrict__ ssrc,
    const float* __restrict__ bias, _Float16* __restrict__ hB, int N) {
  const int lane = threadIdx.x & 63;
  const int n = blockIdx.x * 4 + (threadIdx.x >> 6);
  if (n >= N) return;
  const int gq = lane >> 4;
  const int l = lane & 15;
  const int b0 = base[n], b1 = base[n + 1];

  int e = b0;
  int p0 = e + gq, p1 = e + 4 + gq;
  int i0 = ssrc[p0], i1 = ssrc[p1];          // +16 slack makes loads safe
  i0 = (p0 < b1) ? i0 : N;
  i1 = (p1 < b1) ? i1 : N;
  v8hf r0 = *(const v8hf*)(g + (size_t)i0 * NFEAT + l * 8);
  v8hf r1 = *(const v8hf*)(g + (size_t)i1 * NFEAT + l * 8);
  int e2 = e + 8;
  int j0 = N, j1 = N;
  if (e2 < b1) {
    int q0 = e2 + gq, q1 = e2 + 4 + gq;
    j0 = ssrc[q0]; j1 = ssrc[q1];
    j0 = (q0 < b1) ? j0 : N;
    j1 = (q1 < b1) ? j1 : N;
  }

  float acc[8] = {};
  while (true) {
    bool more = (e2 < b1);
    v8hf s0, s1;
    if (more) {                       // issue iter k+1 gathers before consuming k
      s0 = *(const v8hf*)(g + (size_t)j0 * NFEAT + l * 8);
      s1 = *(const v8hf*)(g + (size_t)j1 * NFEAT + l * 8);
    }
    int e3 = e2 + 8;
    int c0 = N, c1 = N;
    if (e3 < b1) {                    // iter k+2 indices
      int q0 = e3 + gq, q1 = e3 + 4 + gq;
      c0 = ssrc[q0]; c1 = ssrc[q1];
      c0 = (q0 < b1) ? c0 : N;
      c1 = (q1 < b1) ? c1 : N;
    }
    #pragma unroll
    for (int j = 0; j < 8; j++) acc[j] += (float)r0[j] + (float)r1[j];
    if (!more) break;
    r0 = s0; r1 = s1;
    j0 = c0; j1 = c1;
    e2 = e3;
  }

  #pragma unroll
  for (int j = 0; j < 8; j++) {
    acc[j] += __shfl_xor(acc[j], 16, 64);
    acc[j] += __shfl_xor(acc[j], 32, 64);
  }
  if (gq == 0) {
    float dvn = dinv[n];
    const float* bp = bias + l * 8;
    float4 bb0 = *(const float4*)(bp);
    float4 bb1 = *(const float4*)(bp + 4);
    float bv[8] = {bb0.x, bb0.y, bb0.z, bb0.w, bb1.x, bb1.y, bb1.z, bb1.w};
    v8hf o;
    #pragma unroll
    for (int j = 0; j < 8; j++)
      o[j] = (_Float16)fmaxf(acc[j] * dvn + bv[j], 0.f);
    *(v8hf*)(hB + (size_t)n * NFEAT + l * 8) = o;
  }
}

// ---------------- layer-2 agg fused with final linear (same pipeline) --------
__global__ __launch_bounds__(256) void k_agg_final(
    const _Float16* __restrict__ g, const float* __restrict__ dinv,
    const int* __restrict__ base, const int* __restrict__ ssrc,
    const float* __restrict__ bias, const float* __restrict__ wlin,
    const float* __restrict__ blin, float* __restrict__ out, int N) {
  const int lane = threadIdx.x & 63;
  const int n = blockIdx.x * 4 + (threadIdx.x >> 6);
  if (n >= N) return;
  const int gq = lane >> 4;
  const int l = lane & 15;
  const int b0 = base[n], b1 = base[n + 1];

  int e = b0;
  int p0 = e + gq, p1 = e + 4 + gq;
  int i0 = ssrc[p0], i1 = ssrc[p1];
  i0 = (p0 < b1) ? i0 : N;
  i1 = (p1 < b1) ? i1 : N;
  v8hf r0 = *(const v8hf*)(g + (size_t)i0 * NFEAT + l * 8);
  v8hf r1 = *(const v8hf*)(g + (size_t)i1 * NFEAT + l * 8);
  int e2 = e + 8;
  int j0 = N, j1 = N;
  if (e2 < b1) {
    int q0 = e2 + gq, q1 = e2 + 4 + gq;
    j0 = ssrc[q0]; j1 = ssrc[q1];
    j0 = (q0 < b1) ? j0 : N;
    j1 = (q1 < b1) ? j1 : N;
  }

  float acc[8] = {};
  while (true) {
    bool more = (e2 < b1);
    v8hf s0, s1;
    if (more) {
      s0 = *(const v8hf*)(g + (size_t)j0 * NFEAT + l * 8);
      s1 = *(const v8hf*)(g + (size_t)j1 * NFEAT + l * 8);
    }
    int e3 = e2 + 8;
    int c0 = N, c1 = N;
    if (e3 < b1) {
      int q0 = e3 + gq, q1 = e3 + 4 + gq;
      c0 = ssrc[q0]; c1 = ssrc[q1];
      c0 = (q0 < b1) ? c0 : N;
      c1 = (q1 < b1) ? c1 : N;
    }
    #pragma unroll
    for (int j = 0; j < 8; j++) acc[j] += (float)r0[j] + (float)r1[j];
    if (!more) break;
    r0 = s0; r1 = s1;
    j0 = c0; j1 = c1;
    e2 = e3;
  }

  #pragma unroll
  for (int j = 0; j < 8; j++) {
    acc[j] += __shfl_xor(acc[j], 16, 64);
    acc[j] += __shfl_xor(acc[j], 32, 64);
  }
  float dvn = dinv[n];
  const float* bp = bias + l * 8;
  const float* wp = wlin + l * 8;
  float4 bb0 = *(const float4*)(bp);
  float4 bb1 = *(const float4*)(bp + 4);
  float4 wl0 = *(const float4*)(wp);
  float4 wl1 = *(const float4*)(wp + 4);
  float bv[8] = {bb0.x, bb0.y, bb0.z, bb0.w, bb1.x, bb1.y, bb1.z, bb1.w};
  float wv[8] = {wl0.x, wl0.y, wl0.z, wl0.w, wl1.x, wl1.y, wl1.z, wl1.w};
  float pv = 0.f;
  #pragma unroll
  for (int j = 0; j < 8; j++)
    pv += fmaxf(acc[j] * dvn + bv[j], 0.f) * wv[j];
  pv += __shfl_xor(pv, 1, 64);
  pv += __shfl_xor(pv, 2, 64);
  pv += __shfl_xor(pv, 4, 64);
  pv += __shfl_xor(pv, 8, 64);
  if (lane == 0) out[n] = pv + blin[0];
}

extern "C" void kernel_launch(void* const* d_in, const int* in_sizes, int n_in,
                              void* d_out, int out_size, void* d_ws, size_t ws_size,
                              hipStream_t stream) {
  const float* x    = (const float*)d_in[0];
  const int*   ei   = (const int*)d_in[1];
  const float* W1   = (const float*)d_in[2];
  const float* b1   = (const float*)d_in[3];
  const float* W2   = (const float*)d_in[4];
  const float* b2   = (const float*)d_in[5];
  const float* Wlin = (const float*)d_in[6];
  const float* blin = (const float*)d_in[7];
  const int N = in_sizes[0] / NFEAT;
  const int E = in_sizes[1] / 2;
  const int* src = ei;
  const int* dst = ei + E;
  const int Etot = E + N;                  // real edges + self edges
  const int nb = (N + BSZ - 1) >> BSH;     // #buckets (<=256 for N<=131072)

  // workspace layout (4B units)
  int* ws_i = (int*)d_ws;
  size_t off = 0;
  int* base    = ws_i + off; off += (size_t)N + 1;
  int* ghist   = ws_i + off; off += 256;
  int* ebase   = ws_i + off; off += 257;
  int* sbase   = ws_i + off; off += 257;
  int* cursor  = ws_i + off; off += 257;
  int* ssrc    = ws_i + off; off += Etot + 16;   // +16 slack for tail loads
  float* dinv  = (float*)(ws_i + off); off += N;
  off = (off + 3) & ~(size_t)3;
  _Float16* Wt1 = (_Float16*)(ws_i + off); off += 8192;  // 16384 halves
  _Float16* Wt2 = (_Float16*)(ws_i + off); off += 8192;
  _Float16* g16 = (_Float16*)(ws_i + off); off += (size_t)(N + 1) * 64; // +sentinel
  off = (off + 1) & ~(size_t)1;                  // 8B align for epk alias
  _Float16* hB  = (_Float16*)(ws_i + off); off += (size_t)N * 64;
  // epk aliases hB: written by k_bscatter, read by k_bfinal, dead before k_agg
  // writes hB. Needs Etot*8B = 13.3MB <= hB's 25.6MB.
  unsigned long long* epk = (unsigned long long*)hB;

  // 1. W transpose + zero bucket histogram
  k_wt<<<129, 256, 0, stream>>>(W1, W2, Wt1, Wt2, ghist);
  // 2. coarse bucket histogram (LDS atomics, 1 global atomic/(blk,bucket))
  const int ebg = (E + EPB - 1) / EPB;
  k_bhist<<<ebg, 256, 0, stream>>>(dst, ghist, E);
  // 3. scan bucket totals
  k_bscan<<<1, 256, 0, stream>>>(ghist, ebase, sbase, cursor, base, nb, N);
  // 4. partition edges into bucket order (packed 8B records)
  k_bscatter<<<ebg, 256, 0, stream>>>(src, dst, cursor, epk, E);
  // 5. per-bucket node histogram -> base/dinv/self/ssrc (all LDS atomics)
  k_bfinal<<<nb, 256, 0, stream>>>(epk, ebase, sbase, base, dinv, ssrc, N);

  const int gg = (N + 63) / 64;
  const int ga = (N + 3) / 4;
  // layer 1
  k_gemm_mfma<float><<<gg, 256, 0, stream>>>(x, Wt1, dinv, g16, N);
  k_agg<<<ga, 256, 0, stream>>>(g16, dinv, base, ssrc, b1, hB, N);
  // layer 2 + fused final linear
  k_gemm_mfma<_Float16><<<gg, 256, 0, stream>>>(hB, Wt2, dinv, g16, N);
  k_agg_final<<<ga, 256, 0, stream>>>(g16, dinv, base, ssrc, b2,
                                      Wlin, blin, (float*)d_out, N);
}